// Round 4
// baseline (232.180 us; speedup 1.0000x reference)
//
#include <hip/hip_runtime.h>
#include <hip/hip_bf16.h>
#include <stdint.h>

using bf16 = __hip_bfloat16;
typedef __attribute__((ext_vector_type(8))) short bf16x8;   // 8 bf16 raw bits (4 VGPRs)
typedef __attribute__((ext_vector_type(4))) float f32x4;

__device__ __forceinline__ void async_load16(const void* g, void* l) {
    __builtin_amdgcn_global_load_lds(
        (__attribute__((address_space(1))) const void*)g,
        (__attribute__((address_space(3))) void*)l,
        16, 0, 0);
}

// ---------------- prep: all weight converts in one launch ----------------
__device__ __forceinline__ void cvt_block_2048(const float* __restrict__ src,
                                               bf16* __restrict__ dst, int relblk) {
    int i = (relblk * 256 + (int)threadIdx.x) * 8;
    float4 f0 = *(const float4*)(src + i);
    float4 f1 = *(const float4*)(src + i + 4);
    union { bf16 h[8]; uint4 u; } o;
    o.h[0] = __float2bfloat16(f0.x); o.h[1] = __float2bfloat16(f0.y);
    o.h[2] = __float2bfloat16(f0.z); o.h[3] = __float2bfloat16(f0.w);
    o.h[4] = __float2bfloat16(f1.x); o.h[5] = __float2bfloat16(f1.y);
    o.h[6] = __float2bfloat16(f1.z); o.h[7] = __float2bfloat16(f1.w);
    *(uint4*)(dst + i) = o.u;
}

__device__ __forceinline__ void transp_tile(const float* __restrict__ src,
                                            bf16* __restrict__ dst, int R, int C,
                                            int tile, int ntx, bf16 (*sh)[33]) {
    const int bx = (tile % ntx) * 32, by = (tile / ntx) * 32;
    const int lx = threadIdx.x & 31;
    const int ly4 = ((int)threadIdx.x >> 5) * 4;
#pragma unroll
    for (int r = 0; r < 4; ++r)
        sh[ly4 + r][lx] = __float2bfloat16(src[(size_t)(by + ly4 + r) * C + bx + lx]);
    __syncthreads();
#pragma unroll
    for (int r = 0; r < 4; ++r)
        dst[(size_t)(bx + ly4 + r) * R + by + lx] = sh[lx][ly4 + r];
}

__global__ __launch_bounds__(256) void prep(
    const float* __restrict__ w1, bf16* __restrict__ w1b,
    const float* __restrict__ wup, bf16* __restrict__ wub,
    const float* __restrict__ wd, bf16* __restrict__ wdt,
    const float* __restrict__ w2, bf16* __restrict__ w2t) {
    __shared__ bf16 sh[32][33];
    int b = blockIdx.x;
    if (b < 128)        cvt_block_2048(w1, w1b, b);                   // 512x512
    else if (b < 640)   cvt_block_2048(wup, wub, b - 128);            // 2048x512
    else if (b < 1664)  transp_tile(wd, wdt, 512, 2048, b - 640, 64, sh);  // Wd^T [2048x512]
    else                transp_tile(w2, w2t, 512, 512, b - 1664, 16, sh);  // W2^T [512x512]
}

// ---------------- GEMM core: C[MxN] = A[MxK] * B[NxK]^T ----------------
// BM=128, BK=64, BN in {64,128}. XOR-swizzled LDS: global (row, col8) lives at
// 16B-chunk index row*8 + (col8 ^ (row&7)). global_load_lds staging keeps the
// wave's LDS dest contiguous (lane*16) while the swizzle is applied to the
// global source address (8-lane groups still cover one contiguous 128B row-seg).
// AFP32: A is fp32, converted to bf16 in-register and ds_write'd (same layout).
// EPI==0: store bf16 to Cb.  EPI==1: Cf[idx] = Res[idx] + (*sp)*acc (fp32).
template<int BN, int EPI, bool AFP32>
__device__ __forceinline__ void gemm_core(
    const void* __restrict__ Aptr, const bf16* __restrict__ B,
    bf16* __restrict__ Cb, float* __restrict__ Cf,
    const float* __restrict__ Res, const float* __restrict__ sp,
    int N, int K, int bxi, int byi, bf16* As, bf16* Bs)
{
    constexpr int BM = 128;
    constexpr int NJ = BN / 32;
    static_assert(BN == 64 || BN == 128, "BN");

    const int tid  = threadIdx.x;
    const int wave = tid >> 6;
    const int lane = tid & 63;
    const int wm = wave >> 1, wn = wave & 1;
    const size_t bm = (size_t)bxi * BM;
    const size_t bn = (size_t)byi * BN;

    f32x4 acc[4][NJ];
#pragma unroll
    for (int i = 0; i < 4; ++i)
#pragma unroll
        for (int j = 0; j < NJ; ++j)
            acc[i][j] = (f32x4){0.f, 0.f, 0.f, 0.f};

    // async staging: one call = 8 rows x 64 cols (1024B); lane -> row lane>>3,
    // phys chunk lane&7, global col8 = (lane&7) ^ (lane>>3)
    const int srow  = lane >> 3;
    const int scol8 = (lane & 7) ^ srow;
    // fp32-A staging: thread -> row tid>>2 (+p*64), quarter tid&3 (16 fp32)
    const int arow = tid >> 2;
    const int aq   = tid & 3;

    for (int k0 = 0; k0 < K; k0 += 64) {
        if (AFP32) {
            const float* Af = (const float*)Aptr;
#pragma unroll
            for (int p = 0; p < 2; ++p) {
                const int row = p * 64 + arow;
                const float* s = Af + (bm + row) * (size_t)K + k0 + aq * 16;
                float4 f0 = *(const float4*)(s);
                float4 f1 = *(const float4*)(s + 4);
                float4 f2 = *(const float4*)(s + 8);
                float4 f3 = *(const float4*)(s + 12);
                union { bf16 h[8]; uint4 u; } o0, o1;
                o0.h[0] = __float2bfloat16(f0.x); o0.h[1] = __float2bfloat16(f0.y);
                o0.h[2] = __float2bfloat16(f0.z); o0.h[3] = __float2bfloat16(f0.w);
                o0.h[4] = __float2bfloat16(f1.x); o0.h[5] = __float2bfloat16(f1.y);
                o0.h[6] = __float2bfloat16(f1.z); o0.h[7] = __float2bfloat16(f1.w);
                o1.h[0] = __float2bfloat16(f2.x); o1.h[1] = __float2bfloat16(f2.y);
                o1.h[2] = __float2bfloat16(f2.z); o1.h[3] = __float2bfloat16(f2.w);
                o1.h[4] = __float2bfloat16(f3.x); o1.h[5] = __float2bfloat16(f3.y);
                o1.h[6] = __float2bfloat16(f3.z); o1.h[7] = __float2bfloat16(f3.w);
                const int r7 = row & 7;
                *(uint4*)&As[(size_t)(row * 8 + ((2 * aq) ^ r7)) * 8]     = o0.u;
                *(uint4*)&As[(size_t)(row * 8 + ((2 * aq + 1) ^ r7)) * 8] = o1.u;
            }
#pragma unroll
            for (int c = 0; c < BN / 32; ++c) {   // B: BN/8 calls over 4 waves
                const int cc = wave + c * 4;
                const int rb = cc * 8;
                async_load16(B + (bn + rb + srow) * (size_t)K + k0 + scol8 * 8, &Bs[rb * 64]);
            }
        } else {
            const bf16* Ab = (const bf16*)Aptr;
            constexpr int TOT = (BM + BN) / 8;    // total 8-row staging calls
#pragma unroll
            for (int c = 0; c < TOT / 4; ++c) {
                const int cc = wave + c * 4;
                if (cc < BM / 8) {
                    const int rb = cc * 8;
                    async_load16(Ab + (bm + rb + srow) * (size_t)K + k0 + scol8 * 8, &As[rb * 64]);
                } else {
                    const int rb = (cc - BM / 8) * 8;
                    async_load16(B + (bn + rb + srow) * (size_t)K + k0 + scol8 * 8, &Bs[rb * 64]);
                }
            }
        }
        __syncthreads();

#pragma unroll
        for (int kk = 0; kk < 2; ++kk) {
            bf16x8 af[4], bfr[NJ];
#pragma unroll
            for (int i = 0; i < 4; ++i) {
                const int r  = wm * 64 + i * 16 + (lane & 15);
                const int c8 = kk * 4 + (lane >> 4);
                af[i] = *(const bf16x8*)&As[(size_t)(r * 8 + (c8 ^ (r & 7))) * 8];
            }
#pragma unroll
            for (int j = 0; j < NJ; ++j) {
                const int r  = wn * (BN / 2) + j * 16 + (lane & 15);
                const int c8 = kk * 4 + (lane >> 4);
                bfr[j] = *(const bf16x8*)&Bs[(size_t)(r * 8 + (c8 ^ (r & 7))) * 8];
            }
#pragma unroll
            for (int i = 0; i < 4; ++i)
#pragma unroll
                for (int j = 0; j < NJ; ++j)
                    acc[i][j] = __builtin_amdgcn_mfma_f32_16x16x32_bf16(af[i], bfr[j], acc[i][j], 0, 0, 0);
        }
        __syncthreads();
    }

    // C/D layout: col = lane&15, row = (lane>>4)*4 + reg
    const int col_l = lane & 15;
    const int row_l = (lane >> 4) * 4;
    if (EPI == 0) {
#pragma unroll
        for (int i = 0; i < 4; ++i)
#pragma unroll
            for (int j = 0; j < NJ; ++j)
#pragma unroll
                for (int r = 0; r < 4; ++r) {
                    size_t row = bm + wm * 64 + i * 16 + row_l + r;
                    size_t col = bn + wn * (BN / 2) + j * 16 + col_l;
                    Cb[row * (size_t)N + col] = __float2bfloat16(acc[i][j][r]);
                }
    } else {
        const float s = *sp;
#pragma unroll
        for (int i = 0; i < 4; ++i)
#pragma unroll
            for (int j = 0; j < NJ; ++j)
#pragma unroll
                for (int r = 0; r < 4; ++r) {
                    size_t row = bm + wm * 64 + i * 16 + row_l + r;
                    size_t col = bn + wn * (BN / 2) + j * 16 + col_l;
                    size_t idx = row * (size_t)N + col;
                    Cf[idx] = Res[idx] + s * acc[i][j][r];
                }
    }
}

// N-tile is blockIdx.x (fastest) so co-dispatched blocks share the same A slab.
template<int BN, int EPI>
__global__ __launch_bounds__(256) void gemm_bf16(
    const bf16* __restrict__ A, const bf16* __restrict__ B,
    bf16* __restrict__ Cb, float* __restrict__ Cf,
    const float* __restrict__ Res, const float* __restrict__ sp, int N, int K) {
    __shared__ __align__(16) bf16 As[128 * 64];
    __shared__ __align__(16) bf16 Bs[BN * 64];
    gemm_core<BN, EPI, false>(A, B, Cb, Cf, Res, sp, N, K, blockIdx.y, blockIdx.x, As, Bs);
}

// x = hs(fp32, converted in-register) * R^T, bf16 out
__global__ __launch_bounds__(256) void gemm_xf32(
    const float* __restrict__ A, const bf16* __restrict__ B,
    bf16* __restrict__ Cb, int N, int K) {
    __shared__ __align__(16) bf16 As[128 * 64];
    __shared__ __align__(16) bf16 Bs[64 * 64];
    gemm_core<64, 0, true>(A, B, Cb, nullptr, nullptr, nullptr, N, K, blockIdx.y, blockIdx.x, As, Bs);
}

// R = W1*Wd and U = Wup*W2 in one launch (independent; both 128x64-tiled)
__global__ __launch_bounds__(256) void gemm_ru(
    const bf16* __restrict__ A0, const bf16* __restrict__ B0, bf16* __restrict__ C0,
    int N0, int K0, int nb0, int nt0,
    const bf16* __restrict__ A1, const bf16* __restrict__ B1, bf16* __restrict__ C1,
    int N1, int K1, int nt1) {
    __shared__ __align__(16) bf16 As[128 * 64];
    __shared__ __align__(16) bf16 Bs[64 * 64];
    int b = blockIdx.x;
    if (b < nb0)
        gemm_core<64, 0, false>(A0, B0, C0, nullptr, nullptr, nullptr, N0, K0,
                                b / nt0, b % nt0, As, Bs);
    else {
        b -= nb0;
        gemm_core<64, 0, false>(A1, B1, C1, nullptr, nullptr, nullptr, N1, K1,
                                b / nt1, b % nt1, As, Bs);
    }
}

extern "C" void kernel_launch(void* const* d_in, const int* in_sizes, int n_in,
                              void* d_out, int out_size, void* d_ws, size_t ws_size,
                              hipStream_t stream) {
    // setup_inputs() order: hidden_states, w_down, w_up, w1, w2, residual_scale
    const float* hs     = (const float*)d_in[0];   // [8192, 2048]
    const float* w_down = (const float*)d_in[1];   // [512, 2048]
    const float* w_up   = (const float*)d_in[2];   // [2048, 512]
    const float* w1     = (const float*)d_in[3];   // [512, 512]
    const float* w2     = (const float*)d_in[4];   // [512, 512]
    const float* rs     = (const float*)d_in[5];   // scalar on device

    char* ws = (char*)d_ws;
    bf16* x_b   = (bf16*)(ws + 0);          //  8,388,608  x [8192x512]
    bf16* w1_b  = (bf16*)(ws + 8388608);    //    524,288  W1 [512x512]
    bf16* wu_b  = (bf16*)(ws + 8912896);    //  2,097,152  Wup [2048x512]
    bf16* wdt_b = (bf16*)(ws + 11010048);   //  2,097,152  Wd^T [2048x512]
    bf16* w2t_b = (bf16*)(ws + 13107200);   //    524,288  W2^T [512x512]
    bf16* Rm    = (bf16*)(ws + 13631488);   //  2,097,152  R = W1*Wd [512x2048]
    bf16* Um    = (bf16*)(ws + 15728640);   //  2,097,152  U = Wup*W2 [2048x512]

    // 1) all weight converts/transposes
    prep<<<dim3(1920), dim3(256), 0, stream>>>(w1, w1_b, w_up, wu_b, w_down, wdt_b, w2, w2t_b);
    // 2) R = NT(W1, Wd^T): M=512,N=2048,K=512 (4 M-tiles x 32 N-tiles = 128 blocks)
    //    U = NT(Wup, W2^T): M=2048,N=512,K=512 (16 x 8 = 128 blocks)
    gemm_ru<<<dim3(256), dim3(256), 0, stream>>>(w1_b, wdt_b, Rm, 2048, 512, 128, 32,
                                                 wu_b, w2t_b, Um, 512, 512, 8);
    // 3) x = NT(hs_fp32, R): M=8192,N=512,K=2048, BN=64 -> grid (Ntiles=8, Mtiles=64)
    gemm_xf32<<<dim3(8, 64), dim3(256), 0, stream>>>(hs, Rm, x_b, 512, 2048);
    // 4) out = res + s*NT(x, U): M=8192,N=2048,K=512, BN=128 -> grid (16, 64)
    gemm_bf16<128, 1><<<dim3(16, 64), dim3(256), 0, stream>>>(x_b, Um, nullptr, (float*)d_out,
                                                              hs, rs, 2048, 512);
}

// Round 5
// 218.474 us; speedup vs baseline: 1.0627x; 1.0627x over previous
//
#include <hip/hip_runtime.h>
#include <hip/hip_bf16.h>
#include <stdint.h>

using bf16 = __hip_bfloat16;
typedef __attribute__((ext_vector_type(8))) short bf16x8;   // 8 bf16 raw bits (4 VGPRs)
typedef __attribute__((ext_vector_type(4))) float f32x4;

__device__ __forceinline__ void async_load16(const void* g, void* l) {
    __builtin_amdgcn_global_load_lds(
        (__attribute__((address_space(1))) const void*)g,
        (__attribute__((address_space(3))) void*)l,
        16, 0, 0);
}

// ---------------- prep: hs convert + all weight converts, one launch ----------------
__device__ __forceinline__ void cvt_block_2048(const float* __restrict__ src,
                                               bf16* __restrict__ dst, int relblk) {
    int i = (relblk * 256 + (int)threadIdx.x) * 8;
    float4 f0 = *(const float4*)(src + i);
    float4 f1 = *(const float4*)(src + i + 4);
    union { bf16 h[8]; uint4 u; } o;
    o.h[0] = __float2bfloat16(f0.x); o.h[1] = __float2bfloat16(f0.y);
    o.h[2] = __float2bfloat16(f0.z); o.h[3] = __float2bfloat16(f0.w);
    o.h[4] = __float2bfloat16(f1.x); o.h[5] = __float2bfloat16(f1.y);
    o.h[6] = __float2bfloat16(f1.z); o.h[7] = __float2bfloat16(f1.w);
    *(uint4*)(dst + i) = o.u;
}

__device__ __forceinline__ void transp_tile(const float* __restrict__ src,
                                            bf16* __restrict__ dst, int R, int C,
                                            int tile, int ntx, bf16 (*sh)[33]) {
    const int bx = (tile % ntx) * 32, by = (tile / ntx) * 32;
    const int lx = threadIdx.x & 31;
    const int ly4 = ((int)threadIdx.x >> 5) * 4;
#pragma unroll
    for (int r = 0; r < 4; ++r)
        sh[ly4 + r][lx] = __float2bfloat16(src[(size_t)(by + ly4 + r) * C + bx + lx]);
    __syncthreads();
#pragma unroll
    for (int r = 0; r < 4; ++r)
        dst[(size_t)(bx + ly4 + r) * R + by + lx] = sh[lx][ly4 + r];
}

__global__ __launch_bounds__(256) void prep(
    const float* __restrict__ hs, bf16* __restrict__ hsb,
    const float* __restrict__ w1, bf16* __restrict__ w1b,
    const float* __restrict__ wup, bf16* __restrict__ wub,
    const float* __restrict__ wd, bf16* __restrict__ wdt,
    const float* __restrict__ w2, bf16* __restrict__ w2t) {
    __shared__ bf16 sh[32][33];
    int b = blockIdx.x;
    if (b < 8192)       cvt_block_2048(hs, hsb, b);                        // hs 8192x2048
    else if (b < 8320)  cvt_block_2048(w1, w1b, b - 8192);                 // W1 512x512
    else if (b < 8832)  cvt_block_2048(wup, wub, b - 8320);                // Wup 2048x512
    else if (b < 9856)  transp_tile(wd, wdt, 512, 2048, b - 8832, 64, sh); // Wd^T
    else                transp_tile(w2, w2t, 512, 512, b - 9856, 16, sh);  // W2^T
}

// ---------------- GEMM core: C[MxN] = A[MxK] * B[NxK]^T, bf16, BM=128, BK=64 ----------------
// XOR-swizzled LDS: global (row, col8) -> 16B-chunk row*8 + (col8 ^ (row&7)).
// global_load_lds keeps wave-contiguous LDS dest; swizzle applied to global source addr.
// EPI==0: bf16 store to Cb (scalar).  EPI==1: LDS-transposed fp32 epilogue,
// Cf = Res + s*acc with float4 (128B-coalesced) loads/stores.
template<int BN, int EPI>
__device__ __forceinline__ void gemm_core(
    const bf16* __restrict__ A, const bf16* __restrict__ B,
    bf16* __restrict__ Cb, float* __restrict__ Cf,
    const float* __restrict__ Res, const float* __restrict__ sp,
    int N, int K, int bxi, int byi, bf16* As, bf16* Bs)
{
    constexpr int BM = 128;
    constexpr int NJ = BN / 32;
    static_assert(BN == 64 || BN == 128, "BN");

    const int tid  = threadIdx.x;
    const int wave = tid >> 6;
    const int lane = tid & 63;
    const int wm = wave >> 1, wn = wave & 1;
    const size_t bm = (size_t)bxi * BM;
    const size_t bn = (size_t)byi * BN;

    f32x4 acc[4][NJ];
#pragma unroll
    for (int i = 0; i < 4; ++i)
#pragma unroll
        for (int j = 0; j < NJ; ++j)
            acc[i][j] = (f32x4){0.f, 0.f, 0.f, 0.f};

    // staging: one call = 8 rows x 64 cols (1024B); lane -> row lane>>3,
    // phys chunk lane&7, global col8 = (lane&7) ^ (lane>>3)
    const int srow  = lane >> 3;
    const int scol8 = (lane & 7) ^ srow;

    for (int k0 = 0; k0 < K; k0 += 64) {
        constexpr int TOT = (BM + BN) / 8;
#pragma unroll
        for (int c = 0; c < TOT / 4; ++c) {
            const int cc = wave + c * 4;
            if (cc < BM / 8) {
                const int rb = cc * 8;
                async_load16(A + (bm + rb + srow) * (size_t)K + k0 + scol8 * 8, &As[rb * 64]);
            } else {
                const int rb = (cc - BM / 8) * 8;
                async_load16(B + (bn + rb + srow) * (size_t)K + k0 + scol8 * 8, &Bs[rb * 64]);
            }
        }
        __syncthreads();

#pragma unroll
        for (int kk = 0; kk < 2; ++kk) {
            bf16x8 af[4], bfr[NJ];
#pragma unroll
            for (int i = 0; i < 4; ++i) {
                const int r  = wm * 64 + i * 16 + (lane & 15);
                const int c8 = kk * 4 + (lane >> 4);
                af[i] = *(const bf16x8*)&As[(size_t)(r * 8 + (c8 ^ (r & 7))) * 8];
            }
#pragma unroll
            for (int j = 0; j < NJ; ++j) {
                const int r  = wn * (BN / 2) + j * 16 + (lane & 15);
                const int c8 = kk * 4 + (lane >> 4);
                bfr[j] = *(const bf16x8*)&Bs[(size_t)(r * 8 + (c8 ^ (r & 7))) * 8];
            }
#pragma unroll
            for (int i = 0; i < 4; ++i)
#pragma unroll
                for (int j = 0; j < NJ; ++j)
                    acc[i][j] = __builtin_amdgcn_mfma_f32_16x16x32_bf16(af[i], bfr[j], acc[i][j], 0, 0, 0);
        }
        __syncthreads();
    }

    // C/D layout: col = lane&15, row = (lane>>4)*4 + reg
    const int col_l = lane & 15;
    const int row_l = (lane >> 4) * 4;
    if (EPI == 0) {
#pragma unroll
        for (int i = 0; i < 4; ++i)
#pragma unroll
            for (int j = 0; j < NJ; ++j)
#pragma unroll
                for (int r = 0; r < 4; ++r) {
                    size_t row = bm + wm * 64 + i * 16 + row_l + r;
                    size_t col = bn + wn * (BN / 2) + j * 16 + col_l;
                    Cb[row * (size_t)N + col] = __float2bfloat16(acc[i][j][r]);
                }
    } else {
        // per-wave 16x64 fp32 slice in LDS (stride 68 breaks bank aliasing,
        // keeps float4 alignment); reuse As/Bs (K-loop done, last barrier passed)
        const float s = *sp;
        float* lds_f = (float*)As + wave * (16 * 68);
#pragma unroll
        for (int i = 0; i < 4; ++i) {
#pragma unroll
            for (int j = 0; j < NJ; ++j)
#pragma unroll
                for (int r = 0; r < 4; ++r)
                    lds_f[(row_l + r) * 68 + j * 16 + col_l] = acc[i][j][r];
            __syncthreads();   // writes visible before cross-lane reads
#pragma unroll
            for (int rh = 0; rh < 2; ++rh)
#pragma unroll
                for (int ch = 0; ch < 2; ++ch) {
                    const int r16 = rh * 8 + (lane >> 3);
                    const int cb  = (lane & 7) * 4 + ch * 32;
                    float4 v = *(float4*)&lds_f[r16 * 68 + cb];
                    size_t row = bm + wm * 64 + i * 16 + r16;
                    size_t col = bn + wn * 64 + cb;
                    size_t idx = row * (size_t)N + col;
                    float4 rv = *(const float4*)&Res[idx];
                    float4 o;
                    o.x = rv.x + s * v.x; o.y = rv.y + s * v.y;
                    o.z = rv.z + s * v.z; o.w = rv.w + s * v.w;
                    *(float4*)&Cf[idx] = o;
                }
            __syncthreads();   // reads done before next i overwrites
        }
    }
}

// N-tile is blockIdx.x (fastest) so co-dispatched blocks share the same A slab.
template<int BN, int EPI>
__global__ __launch_bounds__(256) void gemm_bf16(
    const bf16* __restrict__ A, const bf16* __restrict__ B,
    bf16* __restrict__ Cb, float* __restrict__ Cf,
    const float* __restrict__ Res, const float* __restrict__ sp, int N, int K) {
    __shared__ __align__(16) bf16 smem[(128 + BN) * 64];
    gemm_core<BN, EPI>(A, B, Cb, Cf, Res, sp, N, K, blockIdx.y, blockIdx.x,
                       smem, smem + 128 * 64);
}

// R = W1*Wd and U = Wup*W2 in one launch (independent; both 128x64-tiled)
__global__ __launch_bounds__(256) void gemm_ru(
    const bf16* __restrict__ A0, const bf16* __restrict__ B0, bf16* __restrict__ C0,
    int N0, int K0, int nb0, int nt0,
    const bf16* __restrict__ A1, const bf16* __restrict__ B1, bf16* __restrict__ C1,
    int N1, int K1, int nt1) {
    __shared__ __align__(16) bf16 smem[(128 + 64) * 64];
    int b = blockIdx.x;
    if (b < nb0)
        gemm_core<64, 0>(A0, B0, C0, nullptr, nullptr, nullptr, N0, K0,
                         b / nt0, b % nt0, smem, smem + 128 * 64);
    else {
        b -= nb0;
        gemm_core<64, 0>(A1, B1, C1, nullptr, nullptr, nullptr, N1, K1,
                         b / nt1, b % nt1, smem, smem + 128 * 64);
    }
}

extern "C" void kernel_launch(void* const* d_in, const int* in_sizes, int n_in,
                              void* d_out, int out_size, void* d_ws, size_t ws_size,
                              hipStream_t stream) {
    // setup_inputs() order: hidden_states, w_down, w_up, w1, w2, residual_scale
    const float* hs     = (const float*)d_in[0];   // [8192, 2048]
    const float* w_down = (const float*)d_in[1];   // [512, 2048]
    const float* w_up   = (const float*)d_in[2];   // [2048, 512]
    const float* w1     = (const float*)d_in[3];   // [512, 512]
    const float* w2     = (const float*)d_in[4];   // [512, 512]
    const float* rs     = (const float*)d_in[5];   // scalar on device

    char* ws = (char*)d_ws;
    bf16* hs_b  = (bf16*)(ws + 0);          // 33,554,432  hs bf16 [8192x2048]
    bf16* x_b   = (bf16*)(ws + 33554432);   //  8,388,608  x [8192x512]
    bf16* w1_b  = (bf16*)(ws + 41943040);   //    524,288  W1 [512x512]
    bf16* wu_b  = (bf16*)(ws + 42467328);   //  2,097,152  Wup [2048x512]
    bf16* wdt_b = (bf16*)(ws + 44564480);   //  2,097,152  Wd^T [2048x512]
    bf16* w2t_b = (bf16*)(ws + 46661632);   //    524,288  W2^T [512x512]
    bf16* Rm    = (bf16*)(ws + 47185920);   //  2,097,152  R = W1*Wd [512x2048]
    bf16* Um    = (bf16*)(ws + 49283072);   //  2,097,152  U = Wup*W2 [2048x512]

    // 1) hs convert + all weight converts/transposes (one launch)
    prep<<<dim3(10112), dim3(256), 0, stream>>>(hs, hs_b, w1, w1_b, w_up, wu_b,
                                                w_down, wdt_b, w2, w2t_b);
    // 2) R = NT(W1, Wd^T): M=512,N=2048,K=512 (4x32=128 blocks)
    //    U = NT(Wup, W2^T): M=2048,N=512,K=512 (16x8=128 blocks)
    gemm_ru<<<dim3(256), dim3(256), 0, stream>>>(w1_b, wdt_b, Rm, 2048, 512, 128, 32,
                                                 wu_b, w2t_b, Um, 512, 512, 8);
    // 3) x = NT(hs_b, R): M=8192,N=512,K=2048, BN=64 -> grid (8, 64)
    gemm_bf16<64, 0><<<dim3(8, 64), dim3(256), 0, stream>>>(hs_b, Rm, x_b, nullptr,
                                                            nullptr, nullptr, 512, 2048);
    // 4) out = res + s*NT(x, U): M=8192,N=2048,K=512, BN=128 -> grid (16, 64)
    gemm_bf16<128, 1><<<dim3(16, 64), dim3(256), 0, stream>>>(x_b, Um, nullptr, (float*)d_out,
                                                              hs, rs, 2048, 512);
}

// Round 6
// 211.641 us; speedup vs baseline: 1.0970x; 1.0323x over previous
//
#include <hip/hip_runtime.h>
#include <hip/hip_bf16.h>
#include <stdint.h>

using bf16 = __hip_bfloat16;
typedef __attribute__((ext_vector_type(8))) short bf16x8;   // 8 bf16 raw bits (4 VGPRs)
typedef __attribute__((ext_vector_type(4))) float f32x4;

__device__ __forceinline__ void async_load16(const void* g, void* l) {
    __builtin_amdgcn_global_load_lds(
        (__attribute__((address_space(1))) const void*)g,
        (__attribute__((address_space(3))) void*)l,
        16, 0, 0);
}

// ---------------- converts ----------------
__device__ __forceinline__ void cvt_block_2048(const float* __restrict__ src,
                                               bf16* __restrict__ dst, int relblk) {
    int i = (relblk * 256 + (int)threadIdx.x) * 8;
    float4 f0 = *(const float4*)(src + i);
    float4 f1 = *(const float4*)(src + i + 4);
    union { bf16 h[8]; uint4 u; } o;
    o.h[0] = __float2bfloat16(f0.x); o.h[1] = __float2bfloat16(f0.y);
    o.h[2] = __float2bfloat16(f0.z); o.h[3] = __float2bfloat16(f0.w);
    o.h[4] = __float2bfloat16(f1.x); o.h[5] = __float2bfloat16(f1.y);
    o.h[6] = __float2bfloat16(f1.z); o.h[7] = __float2bfloat16(f1.w);
    *(uint4*)(dst + i) = o.u;
}

__global__ __launch_bounds__(256) void prep_w(
    const float* __restrict__ w1, bf16* __restrict__ w1b,
    const float* __restrict__ wup, bf16* __restrict__ wub,
    const float* __restrict__ wd, bf16* __restrict__ wdt,
    const float* __restrict__ w2, bf16* __restrict__ w2t) {
    __shared__ bf16 sh[32][33];
    int b = blockIdx.x;
    if (b < 128)       { cvt_block_2048(w1, w1b, b); return; }
    if (b < 640)       { cvt_block_2048(wup, wub, b - 128); return; }
    const float* src; bf16* dst; int R, C, tile, ntx;
    if (b < 1664) { src = wd; dst = wdt; R = 512; C = 2048; tile = b - 640; ntx = 64; }
    else          { src = w2; dst = w2t; R = 512; C = 512;  tile = b - 1664; ntx = 16; }
    const int bx = (tile % ntx) * 32, by = (tile / ntx) * 32;
    const int lx = threadIdx.x & 31;
    const int ly4 = ((int)threadIdx.x >> 5) * 4;
#pragma unroll
    for (int r = 0; r < 4; ++r)
        sh[ly4 + r][lx] = __float2bfloat16(src[(size_t)(by + ly4 + r) * C + bx + lx]);
    __syncthreads();
#pragma unroll
    for (int r = 0; r < 4; ++r)
        dst[(size_t)(bx + ly4 + r) * R + by + lx] = sh[lx][ly4 + r];
}

// ---------------- GEMM core: C[MxN] = A[MxK] * B[NxK]^T, bf16 ----------------
// BM=128, BK=64*NP (NP LDS panels, each XOR-swizzled: (row,col8) -> chunk
// row*8 + (col8 ^ (row&7))). EPI==0: bf16 store. EPI==1: Res-prefetch (i<2)
// + LDS-transposed float4 epilogue: Cf = Res + s*acc.
template<int BN, int EPI, int NP>
__device__ __forceinline__ void gemm_core(
    const bf16* __restrict__ A, const bf16* __restrict__ B,
    bf16* __restrict__ Cb, float* __restrict__ Cf,
    const float* __restrict__ Res, const float* __restrict__ sp,
    int N, int K, int bxi, int byi, bf16* As, bf16* Bs)
{
    constexpr int BM = 128;
    constexpr int NJ = BN / 32;
    static_assert(BN == 64 || BN == 128, "BN");

    const int tid  = threadIdx.x;
    const int wave = tid >> 6;
    const int lane = tid & 63;
    const int wm = wave >> 1, wn = wave & 1;
    const size_t bm = (size_t)bxi * BM;
    const size_t bn = (size_t)byi * BN;

    f32x4 acc[4][NJ];
#pragma unroll
    for (int i = 0; i < 4; ++i)
#pragma unroll
        for (int j = 0; j < NJ; ++j)
            acc[i][j] = (f32x4){0.f, 0.f, 0.f, 0.f};

    const int srow  = lane >> 3;
    const int scol8 = (lane & 7) ^ srow;

    // Res prefetch for i<2 — loads complete during first K-iter (overlap)
    float4 res_pre[EPI ? 8 : 1];
    if (EPI) {
        const int r16 = lane >> 3;
        const int cbb = (lane & 7) * 4;
#pragma unroll
        for (int i = 0; i < 2; ++i)
#pragma unroll
            for (int rh = 0; rh < 2; ++rh)
#pragma unroll
                for (int ch = 0; ch < 2; ++ch) {
                    size_t row = bm + wm * 64 + i * 16 + rh * 8 + r16;
                    size_t col = bn + wn * 64 + cbb + ch * 32;
                    res_pre[i * 4 + rh * 2 + ch] = *(const float4*)&Res[row * (size_t)N + col];
                }
    }

    for (int k0 = 0; k0 < K; k0 += 64 * NP) {
        constexpr int TOT = (BM + BN) / 8;
#pragma unroll
        for (int p = 0; p < NP; ++p)
#pragma unroll
            for (int c = 0; c < TOT / 4; ++c) {
                const int cc = wave + c * 4;
                if (cc < BM / 8) {
                    const int rb = cc * 8;
                    async_load16(A + (bm + rb + srow) * (size_t)K + k0 + p * 64 + scol8 * 8,
                                 &As[p * BM * 64 + rb * 64]);
                } else {
                    const int rb = (cc - BM / 8) * 8;
                    async_load16(B + (bn + rb + srow) * (size_t)K + k0 + p * 64 + scol8 * 8,
                                 &Bs[p * BN * 64 + rb * 64]);
                }
            }
        __syncthreads();

#pragma unroll
        for (int kk = 0; kk < 2 * NP; ++kk) {
            const bf16* Ap = As + (kk >> 1) * BM * 64;
            const bf16* Bp = Bs + (kk >> 1) * BN * 64;
            const int c8 = (kk & 1) * 4 + (lane >> 4);
            bf16x8 af[4], bfr[NJ];
#pragma unroll
            for (int i = 0; i < 4; ++i) {
                const int r = wm * 64 + i * 16 + (lane & 15);
                af[i] = *(const bf16x8*)&Ap[(size_t)(r * 8 + (c8 ^ (r & 7))) * 8];
            }
#pragma unroll
            for (int j = 0; j < NJ; ++j) {
                const int r = wn * (BN / 2) + j * 16 + (lane & 15);
                bfr[j] = *(const bf16x8*)&Bp[(size_t)(r * 8 + (c8 ^ (r & 7))) * 8];
            }
#pragma unroll
            for (int i = 0; i < 4; ++i)
#pragma unroll
                for (int j = 0; j < NJ; ++j)
                    acc[i][j] = __builtin_amdgcn_mfma_f32_16x16x32_bf16(af[i], bfr[j], acc[i][j], 0, 0, 0);
        }
        __syncthreads();
    }

    // C/D layout: col = lane&15, row = (lane>>4)*4 + reg
    const int col_l = lane & 15;
    const int row_l = (lane >> 4) * 4;
    if (EPI == 0) {
#pragma unroll
        for (int i = 0; i < 4; ++i)
#pragma unroll
            for (int j = 0; j < NJ; ++j)
#pragma unroll
                for (int r = 0; r < 4; ++r) {
                    size_t row = bm + wm * 64 + i * 16 + row_l + r;
                    size_t col = bn + wn * (BN / 2) + j * 16 + col_l;
                    Cb[row * (size_t)N + col] = __float2bfloat16(acc[i][j][r]);
                }
    } else {
        // per-wave 16x64 fp32 slice in LDS (stride 68 breaks bank aliasing)
        const float s = *sp;
        float* lds_f = (float*)As + wave * (16 * 68);
#pragma unroll
        for (int i = 0; i < 4; ++i) {
#pragma unroll
            for (int j = 0; j < NJ; ++j)
#pragma unroll
                for (int r = 0; r < 4; ++r)
                    lds_f[(row_l + r) * 68 + j * 16 + col_l] = acc[i][j][r];
            __syncthreads();
#pragma unroll
            for (int rh = 0; rh < 2; ++rh)
#pragma unroll
                for (int ch = 0; ch < 2; ++ch) {
                    const int r16 = rh * 8 + (lane >> 3);
                    const int cb  = (lane & 7) * 4 + ch * 32;
                    float4 v = *(float4*)&lds_f[r16 * 68 + cb];
                    size_t row = bm + wm * 64 + i * 16 + r16;
                    size_t col = bn + wn * 64 + cb;
                    size_t idx = row * (size_t)N + col;
                    float4 rv = (i < 2) ? res_pre[i * 4 + rh * 2 + ch]
                                        : *(const float4*)&Res[idx];
                    float4 o;
                    o.x = rv.x + s * v.x; o.y = rv.y + s * v.y;
                    o.z = rv.z + s * v.z; o.w = rv.w + s * v.w;
                    *(float4*)&Cf[idx] = o;
                }
            __syncthreads();
        }
    }
}

// N-tile is blockIdx.x (fastest) so co-dispatched blocks share the same A slab.
template<int BN, int EPI, int NP>
__global__ __launch_bounds__(256) void gemm_bf16(
    const bf16* __restrict__ A, const bf16* __restrict__ B,
    bf16* __restrict__ Cb, float* __restrict__ Cf,
    const float* __restrict__ Res, const float* __restrict__ sp, int N, int K) {
    __shared__ __align__(16) bf16 smem[(128 + BN) * 64 * NP];
    gemm_core<BN, EPI, NP>(A, B, Cb, Cf, Res, sp, N, K, blockIdx.y, blockIdx.x,
                           smem, smem + 128 * 64 * NP);
}

// R = W1*Wd, U = Wup*W2 (256 blocks) + hs fp32->bf16 convert (8192 blocks), one launch.
__global__ __launch_bounds__(256) void ru_cvt(
    const bf16* __restrict__ A0, const bf16* __restrict__ B0, bf16* __restrict__ C0,
    const bf16* __restrict__ A1, const bf16* __restrict__ B1, bf16* __restrict__ C1,
    const float* __restrict__ hs, bf16* __restrict__ hsb) {
    __shared__ __align__(16) bf16 smem[(128 + 64) * 64];
    int b = blockIdx.x;
    if (b < 128)        // R = NT(W1, Wd^T): M=512,N=2048,K=512, tiles 4x32
        gemm_core<64, 0, 1>(A0, B0, C0, nullptr, nullptr, nullptr, 2048, 512,
                            b / 32, b % 32, smem, smem + 128 * 64);
    else if (b < 256) { // U = NT(Wup, W2^T): M=2048,N=512,K=512, tiles 16x8
        int bb = b - 128;
        gemm_core<64, 0, 1>(A1, B1, C1, nullptr, nullptr, nullptr, 512, 512,
                            bb / 8, bb % 8, smem, smem + 128 * 64);
    } else
        cvt_block_2048(hs, hsb, b - 256);
}

extern "C" void kernel_launch(void* const* d_in, const int* in_sizes, int n_in,
                              void* d_out, int out_size, void* d_ws, size_t ws_size,
                              hipStream_t stream) {
    // setup_inputs() order: hidden_states, w_down, w_up, w1, w2, residual_scale
    const float* hs     = (const float*)d_in[0];   // [8192, 2048]
    const float* w_down = (const float*)d_in[1];   // [512, 2048]
    const float* w_up   = (const float*)d_in[2];   // [2048, 512]
    const float* w1     = (const float*)d_in[3];   // [512, 512]
    const float* w2     = (const float*)d_in[4];   // [512, 512]
    const float* rs     = (const float*)d_in[5];   // scalar on device

    char* ws = (char*)d_ws;
    bf16* hs_b  = (bf16*)(ws + 0);          // 33,554,432  hs bf16 [8192x2048]
    bf16* x_b   = (bf16*)(ws + 33554432);   //  8,388,608  x [8192x512]
    bf16* w1_b  = (bf16*)(ws + 41943040);   //    524,288  W1 [512x512]
    bf16* wu_b  = (bf16*)(ws + 42467328);   //  2,097,152  Wup [2048x512]
    bf16* wdt_b = (bf16*)(ws + 44564480);   //  2,097,152  Wd^T [2048x512]
    bf16* w2t_b = (bf16*)(ws + 46661632);   //    524,288  W2^T [512x512]
    bf16* Rm    = (bf16*)(ws + 47185920);   //  2,097,152  R = W1*Wd [512x2048]
    bf16* Um    = (bf16*)(ws + 49283072);   //  2,097,152  U = Wup*W2 [2048x512]

    // 1) weight converts/transposes only (short critical-path stage)
    prep_w<<<dim3(1920), dim3(256), 0, stream>>>(w1, w1_b, w_up, wu_b, w_down, wdt_b, w2, w2t_b);
    // 2) R,U GEMMs + hs convert folded into one launch
    ru_cvt<<<dim3(256 + 8192), dim3(256), 0, stream>>>(w1_b, wdt_b, Rm, wu_b, w2t_b, Um, hs, hs_b);
    // 3) x = NT(hs_b, R): M=8192,N=512,K=2048, BK=128 (NP=2), grid (8,64)
    gemm_bf16<64, 0, 2><<<dim3(8, 64), dim3(256), 0, stream>>>(hs_b, Rm, x_b, nullptr,
                                                               nullptr, nullptr, 512, 2048);
    // 4) out = res + s*NT(x, U): M=8192,N=2048,K=512, BK=64, grid (16,64)
    gemm_bf16<128, 1, 1><<<dim3(16, 64), dim3(256), 0, stream>>>(x_b, Um, nullptr, (float*)d_out,
                                                                 hs, rs, 2048, 512);
}